// Round 1
// baseline (207.134 us; speedup 1.0000x reference)
//
#include <hip/hip_runtime.h>

// ---------------------------------------------------------------------------
// MalConv: g[m,o] = sum_{k,c} emb[x[m*500+k]][c] * W[o][c][k]  (o in 0..255,
// cols 0..127 = W1 -> g1, cols 128..255 = W2 -> g2), h = relu(g1*sigmoid(g2)),
// m_ws[b][o] = max_p h, out = m_ws @ fcW^T + fcb.
// GEMM: M=16000, K=4000 (r = k*8+c), N=256, bf16 MFMA 16x16x32.
// ---------------------------------------------------------------------------

typedef __attribute__((ext_vector_type(8))) short short8;
typedef __attribute__((ext_vector_type(4))) float f32x4;

__device__ __forceinline__ unsigned short f2b(float f) {
    union { float f; unsigned u; } un;
    un.f = f;
    unsigned u = un.u;
    return (unsigned short)((u + 0x7FFFu + ((u >> 16) & 1u)) >> 16);  // RNE
}

#define KT_COUNT 125                       // K = 4000 = 125 * 32
#define WS_BBLK_BYTES (KT_COUNT * 256 * 32 * 2)   // 2,048,000 B bf16 weights
#define WS_MWS_OFF WS_BBLK_BYTES                  // 8*128 f32 max accumulator

// Pack W1,W2 (fp32 [128][8][500]) into bf16 Bblk[kt][o][j], r = kt*32+j,
// k = r>>3, c = r&7.  One element per thread; 4 MB read total.
__global__ __launch_bounds__(256) void prep_weights(
        const float* __restrict__ W1, const float* __restrict__ W2,
        unsigned short* __restrict__ Bblk) {
    int idx = blockIdx.x * 256 + threadIdx.x;   // 0 .. 1,023,999
    int kt  = idx >> 13;                        // /(256*32)
    int rem = idx & 8191;
    int o   = rem >> 5;
    int j   = rem & 31;
    int r   = kt * 32 + j;
    int k   = r >> 3;
    int c   = r & 7;
    float v = (o < 128) ? W1[o * 4000 + c * 500 + k]
                        : W2[(o - 128) * 4000 + c * 500 + k];
    Bblk[idx] = f2b(v);
}

// Main fused kernel: 250 WGs x 512 threads. WG tile = 64 patches x 256 outs.
// 8 waves, each wave: 64(M) x 32(N) = 4x2 fragments of 16x16x32 bf16 MFMA.
__global__ __launch_bounds__(512, 2) void malconv_main(
        const int* __restrict__ x, const float* __restrict__ emb,
        const float* __restrict__ b1, const float* __restrict__ b2,
        const unsigned short* __restrict__ Bblk, float* __restrict__ m_ws) {
    __shared__ __align__(16) unsigned short embb[257 * 8];   // bf16 emb table
    __shared__ __align__(16) unsigned short Alds[64 * 40];   // 64 x 32 (+8 pad)
    __shared__ __align__(16) unsigned short Blds[256 * 40];  // 256 x 32 (+8 pad)
    __shared__ float g2_lds[64 * 132];                       // epilogue exchange

    const int t = threadIdx.x;
    // bf16 emb table (257 rows x 8 ch = 16 B/row)
    for (int e = t; e < 257 * 8; e += 512) embb[e] = f2b(emb[e]);
    __syncthreads();

    const int m0   = blockIdx.x * 64;
    const int lane = t & 63, wave = t >> 6;
    const int quad = lane >> 4, l16 = lane & 15;

    f32x4 acc[4][2];
#pragma unroll
    for (int mi = 0; mi < 4; ++mi)
#pragma unroll
        for (int ni = 0; ni < 2; ++ni) {
            f32x4 z = {0.f, 0.f, 0.f, 0.f};
            acc[mi][ni] = z;
        }

    // A staging assignment (threads 0..255): patch ai (0..63), k-pos aj (0..3)
    const int ai = t >> 2, aj = t & 3;
    const int* xptr = x + (m0 + ai) * 500 + aj;

    for (int kt = 0; kt < KT_COUNT; ++kt) {
        // ---- stage A: gather emb rows for 64 patches x 4 k-positions ----
        if (t < 256) {
            int xv = xptr[kt * 4];                       // byte value 0..256
            uint4 row = *(const uint4*)&embb[xv * 8];    // 8 bf16 = 16 B
            *(uint4*)&Alds[ai * 40 + aj * 8] = row;
        }
        // ---- stage B: 16 KB blocked weights -> LDS (transposed-[o][j]) ----
        const uint4* bsrc = (const uint4*)(Bblk) + kt * 1024;
#pragma unroll
        for (int cc = 0; cc < 2; ++cc) {
            uint4 v = bsrc[t + cc * 512];
            int oo = (t >> 2) + cc * 128;
            int jj = (t & 3) * 8;
            *(uint4*)&Blds[oo * 40 + jj] = v;
        }
        __syncthreads();
        // ---- fragments + MFMA ----
        short8 afrag[4], bfrag[2];
#pragma unroll
        for (int mi = 0; mi < 4; ++mi)
            afrag[mi] = *(const short8*)&Alds[(mi * 16 + l16) * 40 + quad * 8];
#pragma unroll
        for (int ni = 0; ni < 2; ++ni)
            bfrag[ni] = *(const short8*)&Blds[(wave * 32 + ni * 16 + l16) * 40 + quad * 8];
#pragma unroll
        for (int mi = 0; mi < 4; ++mi)
#pragma unroll
            for (int ni = 0; ni < 2; ++ni)
                acc[mi][ni] = __builtin_amdgcn_mfma_f32_16x16x32_bf16(
                    afrag[mi], bfrag[ni], acc[mi][ni], 0, 0, 0);
        __syncthreads();
    }

    // ---- epilogue: waves 4..7 hold g2 (cols 128..255) -> LDS ----
    if (wave >= 4) {
#pragma unroll
        for (int mi = 0; mi < 4; ++mi)
#pragma unroll
            for (int ni = 0; ni < 2; ++ni)
#pragma unroll
                for (int r = 0; r < 4; ++r)
                    g2_lds[(mi * 16 + quad * 4 + r) * 132 +
                           (wave - 4) * 32 + ni * 16 + l16] = acc[mi][ni][r];
    }
    __syncthreads();
    // waves 0..3 hold g1 (cols 0..127): GLU + segmented max over patches
    if (wave < 4) {
        const int b0 = m0 / 2000;
        const int bsplit = (b0 + 1) * 2000;          // first patch of batch b0+1
        const bool crosses = (m0 + 63) >= bsplit;    // tile straddles boundary?
#pragma unroll
        for (int ni = 0; ni < 2; ++ni) {
            int o = wave * 32 + ni * 16 + l16;
            float bb1 = b1[o], bb2 = b2[o];
            float mx0 = 0.f, mx1 = 0.f;              // h >= 0 always
#pragma unroll
            for (int mi = 0; mi < 4; ++mi)
#pragma unroll
                for (int r = 0; r < 4; ++r) {
                    int ml = mi * 16 + quad * 4 + r;
                    float g1 = acc[mi][ni][r] + bb1;
                    float g2 = g2_lds[ml * 132 + o] + bb2;
                    float h = fmaxf(g1 / (1.f + __expf(-g2)), 0.f);
                    if (m0 + ml >= bsplit) mx1 = fmaxf(mx1, h);
                    else                   mx0 = fmaxf(mx0, h);
                }
            // reduce across the 4 quads (lanes xor 16, 32)
            mx0 = fmaxf(mx0, __shfl_xor(mx0, 16));
            mx0 = fmaxf(mx0, __shfl_xor(mx0, 32));
            mx1 = fmaxf(mx1, __shfl_xor(mx1, 16));
            mx1 = fmaxf(mx1, __shfl_xor(mx1, 32));
            if (quad == 0) {
                // nonneg floats: int compare == float compare
                atomicMax((int*)&m_ws[b0 * 128 + o], __float_as_int(mx0));
                if (crosses)
                    atomicMax((int*)&m_ws[(b0 + 1) * 128 + o], __float_as_int(mx1));
            }
        }
    }
}

// out[b][j] = sum_o m_ws[b][o] * fcW[j][o] + fcb[j]   (16 outputs)
__global__ void fc_kernel(const float* __restrict__ m_ws,
                          const float* __restrict__ fcW,
                          const float* __restrict__ fcb,
                          float* __restrict__ out) {
    int t = threadIdx.x;
    if (t < 16) {
        int b = t >> 1, j = t & 1;
        float s = 0.f;
        for (int o = 0; o < 128; ++o) s += m_ws[b * 128 + o] * fcW[j * 128 + o];
        out[t] = s + fcb[j];
    }
}

extern "C" void kernel_launch(void* const* d_in, const int* in_sizes, int n_in,
                              void* d_out, int out_size, void* d_ws, size_t ws_size,
                              hipStream_t stream) {
    const int*   x   = (const int*)d_in[0];     // [8, 1e6] bytes (0..256)
    const float* emb = (const float*)d_in[1];   // [257, 8]
    const float* W1  = (const float*)d_in[2];   // [128, 8, 500]
    const float* b1  = (const float*)d_in[3];   // [128]
    const float* W2  = (const float*)d_in[4];   // [128, 8, 500]
    const float* b2  = (const float*)d_in[5];   // [128]
    const float* fcW = (const float*)d_in[6];   // [2, 128]
    const float* fcb = (const float*)d_in[7];   // [2]
    float* out = (float*)d_out;                 // [8, 2]

    unsigned short* Bblk = (unsigned short*)d_ws;
    float* m_ws = (float*)((char*)d_ws + WS_MWS_OFF);

    hipMemsetAsync(m_ws, 0, 8 * 128 * sizeof(float), stream);
    prep_weights<<<4000, 256, 0, stream>>>(W1, W2, Bblk);
    malconv_main<<<250, 512, 0, stream>>>(x, emb, b1, b2, Bblk, m_ws);
    fc_kernel<<<1, 64, 0, stream>>>(m_ws, fcW, fcb, out);
}

// Round 2
// 150.058 us; speedup vs baseline: 1.3804x; 1.3804x over previous
//
#include <hip/hip_runtime.h>

// ---------------------------------------------------------------------------
// MalConv fused: GEMM M=16000, K=4000, N=256 (W1||W2) in bf16 MFMA 16x16x32,
// epilogue GLU+relu+segmented-max, then tiny FC.
//
// Round-2 structure: A-fragment == one 16B emb row (gathered via x byte),
// B-fragment == coalesced 16B slice of pre-blocked Bblk -> B goes straight
// global->reg (no LDS), A ping-pong staged in LDS with ONE barrier/iter and
// x prefetched 2 iterations ahead. Wave tile 32Mx64N (2 mi x 4 ni frags).
// ---------------------------------------------------------------------------

typedef __attribute__((ext_vector_type(8))) short short8;
typedef __attribute__((ext_vector_type(4))) float f32x4;

__device__ __forceinline__ unsigned short f2b(float f) {
    union { float f; unsigned u; } un;
    un.f = f;
    unsigned u = un.u;
    return (unsigned short)((u + 0x7FFFu + ((u >> 16) & 1u)) >> 16);  // RNE
}

#define KT_COUNT 125                              // K = 4000 = 125 * 32
#define WS_BBLK_BYTES (KT_COUNT * 256 * 32 * 2)   // 2,048,000 B bf16 weights
#define WS_MWS_OFF WS_BBLK_BYTES                  // 8*128 f32 max accumulator

// Pack W1,W2 (fp32 [128][8][500]) -> bf16 Bblk[kt][o][j]  (r=kt*32+j, k=r>>3,
// c=r&7). One uint4 (8 shorts = one (o,k) pair's 8 channels) per thread;
// writes fully coalesced. Also zero-inits the m_ws max accumulator.
__global__ __launch_bounds__(256) void prep_weights(
        const float* __restrict__ W1, const float* __restrict__ W2,
        unsigned short* __restrict__ Bblk, float* __restrict__ m_ws) {
    int u   = blockIdx.x * 256 + threadIdx.x;     // 0 .. 127,999 (uint4 idx)
    int kt  = u >> 10;                            // /1024
    int rem = u & 1023;
    int o   = rem >> 2;                           // 0..255
    int g   = rem & 3;
    int k   = kt * 4 + g;                         // 0..499
    const float* W = (o < 128) ? W1 : W2;
    int oo = o & 127;
    unsigned short v[8];
#pragma unroll
    for (int c = 0; c < 8; ++c) v[c] = f2b(W[oo * 4000 + c * 500 + k]);
    uint4 pack;
    pack.x = (unsigned)v[0] | ((unsigned)v[1] << 16);
    pack.y = (unsigned)v[2] | ((unsigned)v[3] << 16);
    pack.z = (unsigned)v[4] | ((unsigned)v[5] << 16);
    pack.w = (unsigned)v[6] | ((unsigned)v[7] << 16);
    *(uint4*)&Bblk[u * 8] = pack;
    if (blockIdx.x < 4) m_ws[blockIdx.x * 256 + threadIdx.x] = 0.f;
}

// Main fused kernel: 250 WGs x 512 threads. WG tile = 64 patches x 256 outs.
// Wave w: mq=w>>2 (m half), nq=w&3 (n quarter); frags acc[2][4].
__global__ __launch_bounds__(512, 2) void malconv_main(
        const int* __restrict__ x, const float* __restrict__ emb,
        const float* __restrict__ b1, const float* __restrict__ b2,
        const unsigned short* __restrict__ Bblk, float* __restrict__ m_ws) {
    __shared__ __align__(16) unsigned short embb[257 * 8];     // bf16 emb rows
    __shared__ __align__(16) unsigned short Alds[2][64 * 40];  // ping-pong A
    __shared__ float g2_lds[64 * 132];                         // epilogue xchg

    const int t = threadIdx.x;
    for (int e = t; e < 257 * 8; e += 512) embb[e] = f2b(emb[e]);

    const int m0   = blockIdx.x * 64;
    const int lane = t & 63, wave = t >> 6;
    const int quad = lane >> 4, l16 = lane & 15;
    const int mq   = wave >> 2, nq = wave & 3;

    // B fragment base: rows o = nq*64 + ni*16 + l16, 32 shorts/row, quad*8.
    const unsigned short* bbase = Bblk + (nq * 64 + l16) * 32 + quad * 8;

    f32x4 acc[2][4];
#pragma unroll
    for (int mi = 0; mi < 2; ++mi)
#pragma unroll
        for (int ni = 0; ni < 4; ++ni) {
            f32x4 z = {0.f, 0.f, 0.f, 0.f};
            acc[mi][ni] = z;
        }

    // A staging (threads 0..255 = waves 0..3): row ai (0..63), k-pos aj (0..3)
    const int ai = t >> 2, aj = t & 3;
    const int* xptr = x + (m0 + ai) * 500 + aj;

    __syncthreads();  // embb ready

    // preamble: stage kt=0 into buf 0; preload B(kt=0); prefetch x for kt=1
    int xvn = 0;
    if (t < 256) {
        int xv = xptr[0];
        *(uint4*)&Alds[0][ai * 40 + aj * 8] = *(const uint4*)&embb[xv * 8];
        xvn = xptr[4];
    }
    short8 bcur[4], bnxt[4];
#pragma unroll
    for (int ni = 0; ni < 4; ++ni)
        bcur[ni] = *(const short8*)(bbase + ni * 512);
    __syncthreads();  // buf 0 ready

    for (int kt = 0; kt < KT_COUNT; ++kt) {
        const int cur = kt & 1;
        // prefetch next B tile (issued first; barrier at loop end drains it)
        if (kt < KT_COUNT - 1) {
#pragma unroll
            for (int ni = 0; ni < 4; ++ni)
                bnxt[ni] = *(const short8*)(bbase + (kt + 1) * 8192 + ni * 512);
        }
        // A fragments from LDS
        short8 afrag[2];
#pragma unroll
        for (int mi = 0; mi < 2; ++mi)
            afrag[mi] = *(const short8*)
                &Alds[cur][(mq * 32 + mi * 16 + l16) * 40 + quad * 8];
        // stage next A tile into the other buffer (prev reads of it finished
        // before the barrier that ended the previous iteration)
        if (t < 256 && kt < KT_COUNT - 1) {
            *(uint4*)&Alds[cur ^ 1][ai * 40 + aj * 8] =
                *(const uint4*)&embb[xvn * 8];
            if (kt < KT_COUNT - 2) xvn = xptr[(kt + 2) * 4];
        }
        // MFMA
#pragma unroll
        for (int mi = 0; mi < 2; ++mi)
#pragma unroll
            for (int ni = 0; ni < 4; ++ni)
                acc[mi][ni] = __builtin_amdgcn_mfma_f32_16x16x32_bf16(
                    afrag[mi], bcur[ni], acc[mi][ni], 0, 0, 0);
#pragma unroll
        for (int ni = 0; ni < 4; ++ni) bcur[ni] = bnxt[ni];
        __syncthreads();
    }

    // ---- epilogue: g2 waves (nq>=2, cols 128..255) -> LDS ----
    if (nq >= 2) {
#pragma unroll
        for (int mi = 0; mi < 2; ++mi)
#pragma unroll
            for (int ni = 0; ni < 4; ++ni)
#pragma unroll
                for (int r = 0; r < 4; ++r)
                    g2_lds[(mq * 32 + mi * 16 + quad * 4 + r) * 132 +
                           (nq - 2) * 64 + ni * 16 + l16] = acc[mi][ni][r];
    }
    __syncthreads();
    // g1 waves (nq<2): GLU + segmented max over patches
    if (nq < 2) {
        const int b0 = m0 / 2000;
        const int bsplit = (b0 + 1) * 2000;          // first patch of batch b0+1
        const bool crosses = (m0 + 63) >= bsplit;
#pragma unroll
        for (int ni = 0; ni < 4; ++ni) {
            int o = nq * 64 + ni * 16 + l16;
            float bb1 = b1[o], bb2 = b2[o];
            float mx0 = 0.f, mx1 = 0.f;              // h >= 0 always
#pragma unroll
            for (int mi = 0; mi < 2; ++mi)
#pragma unroll
                for (int r = 0; r < 4; ++r) {
                    int ml = mq * 32 + mi * 16 + quad * 4 + r;
                    float g1 = acc[mi][ni][r] + bb1;
                    float g2 = g2_lds[ml * 132 + o] + bb2;
                    float h = fmaxf(g1 / (1.f + __expf(-g2)), 0.f);
                    if (m0 + ml >= bsplit) mx1 = fmaxf(mx1, h);
                    else                   mx0 = fmaxf(mx0, h);
                }
            mx0 = fmaxf(mx0, __shfl_xor(mx0, 16));
            mx0 = fmaxf(mx0, __shfl_xor(mx0, 32));
            mx1 = fmaxf(mx1, __shfl_xor(mx1, 16));
            mx1 = fmaxf(mx1, __shfl_xor(mx1, 32));
            if (quad == 0) {
                // nonneg floats: int compare == float compare
                atomicMax((int*)&m_ws[b0 * 128 + o], __float_as_int(mx0));
                if (crosses)
                    atomicMax((int*)&m_ws[(b0 + 1) * 128 + o], __float_as_int(mx1));
            }
        }
    }
}

// out[b][j] = sum_o m_ws[b][o] * fcW[j][o] + fcb[j]   (16 outputs)
__global__ void fc_kernel(const float* __restrict__ m_ws,
                          const float* __restrict__ fcW,
                          const float* __restrict__ fcb,
                          float* __restrict__ out) {
    int t = threadIdx.x;
    if (t < 16) {
        int b = t >> 1, j = t & 1;
        float s = 0.f;
        for (int o = 0; o < 128; ++o) s += m_ws[b * 128 + o] * fcW[j * 128 + o];
        out[t] = s + fcb[j];
    }
}

extern "C" void kernel_launch(void* const* d_in, const int* in_sizes, int n_in,
                              void* d_out, int out_size, void* d_ws, size_t ws_size,
                              hipStream_t stream) {
    const int*   x   = (const int*)d_in[0];     // [8, 1e6] values 0..256
    const float* emb = (const float*)d_in[1];   // [257, 8]
    const float* W1  = (const float*)d_in[2];   // [128, 8, 500]
    const float* b1  = (const float*)d_in[3];   // [128]
    const float* W2  = (const float*)d_in[4];   // [128, 8, 500]
    const float* b2  = (const float*)d_in[5];   // [128]
    const float* fcW = (const float*)d_in[6];   // [2, 128]
    const float* fcb = (const float*)d_in[7];   // [2]
    float* out = (float*)d_out;                 // [8, 2]

    unsigned short* Bblk = (unsigned short*)d_ws;
    float* m_ws = (float*)((char*)d_ws + WS_MWS_OFF);

    prep_weights<<<500, 256, 0, stream>>>(W1, W2, Bblk, m_ws);
    malconv_main<<<250, 512, 0, stream>>>(x, emb, b1, b2, Bblk, m_ws);
    fc_kernel<<<1, 64, 0, stream>>>(m_ws, fcW, fcb, out);
}